// Round 7
// baseline (158.865 us; speedup 1.0000x reference)
//
#include <hip/hip_runtime.h>

typedef unsigned short u16;
typedef unsigned int u32;

typedef __bf16 bf16x8 __attribute__((ext_vector_type(8)));
typedef float f32x4 __attribute__((ext_vector_type(4)));

__device__ __forceinline__ u16 f2bf(float f) {
  __bf16 h = (__bf16)f;
  return __builtin_bit_cast(u16, h);
}
__device__ __forceinline__ u32 pk2bf(float a, float b) {
  __bf16 lo = (__bf16)a, hi = (__bf16)b;
  return (u32)__builtin_bit_cast(u16, lo) | ((u32)__builtin_bit_cast(u16, hi) << 16);
}
__device__ __forceinline__ float bf2f(u16 v) {
  u32 u = (u32)v << 16;
  return __builtin_bit_cast(float, u);
}

typedef const __attribute__((address_space(1))) u32 gbl_u32;
typedef __attribute__((address_space(3))) u32 lds_u32;
__device__ __forceinline__ void gload_lds16(const u16* g, u16* l) {
  __builtin_amdgcn_global_load_lds((gbl_u32*)g, (lds_u32*)l, 16, 0, 0);
}

// ---------------- fused f32 -> bf16 convert for all 5 tensors ----------------
__global__ __launch_bounds__(256)
void cvt_all_kernel(const float* __restrict__ x, const float* __restrict__ wq,
                    const float* __restrict__ wk, const float* __restrict__ wv,
                    const float* __restrict__ wo, u16* __restrict__ x_bf,
                    u16* __restrict__ wcat_bf, u16* __restrict__ wo_bf) {
  int t = blockIdx.x * 256 + threadIdx.x;
  const float* src;
  u16* dst;
  if (t < 1048576) {
    src = x; dst = x_bf;
  } else if (t < 1310720) {
    src = wq; dst = wcat_bf; t -= 1048576;
  } else if (t < 1376256) {
    src = wk; dst = wcat_bf + 1048576; t -= 1310720;
  } else if (t < 1441792) {
    src = wv; dst = wcat_bf + 1310720; t -= 1376256;
  } else {
    src = wo; dst = wo_bf; t -= 1441792;
  }
  const int i = t * 4;
  float4 v = *(const float4*)(src + i);
  uint2 p;
  p.x = pk2bf(v.x, v.y);
  p.y = pk2bf(v.z, v.w);
  *(uint2*)(dst + i) = p;
}

// ---------------- bf16 MFMA GEMM: C[M][N] = A[M][K] * B[N][K]^T ----------------
// 64x128 tile, BK=64, 4 waves 2x2 (wave tile 32x64). Double-buffered
// global_load_lds width=16, ONE barrier per K-step. XOR swizzle (blk ^= row&7)
// on the global source address (LDS dest linear); fragment reads same XOR.
// Verified. QKV grid 768 blocks = 3/CU (128^2 tile at 1.5/CU regressed, R5).
template <typename OutT>
__global__ __launch_bounds__(256)
void gemm_bt_kernel(const u16* __restrict__ A, const u16* __restrict__ B,
                    OutT* __restrict__ C, int M, int N, int K) {
  __shared__ u16 As[2][64 * 64];
  __shared__ u16 Bs[2][128 * 64];
  const int tid = threadIdx.x;
  const int lane = tid & 63;
  const int wave = tid >> 6;
  const int wm = (wave >> 1) * 32;
  const int wn = (wave & 1) * 64;
  const int l15 = lane & 15;
  const int quad = lane >> 4;
  const int sw = l15 & 7;
  const size_t bm = (size_t)blockIdx.y * 64;
  const size_t bn = (size_t)blockIdx.x * 128;

  f32x4 acc[2][4];
#pragma unroll
  for (int i = 0; i < 2; ++i)
#pragma unroll
    for (int j = 0; j < 4; ++j) acc[i][j] = f32x4{0.f, 0.f, 0.f, 0.f};

  const int r0 = tid >> 3;
  const int bswz = ((tid & 7) ^ (r0 & 7)) * 8;
  const u16* gA0 = A + (bm + r0) * (size_t)K + bswz;
  const u16* gA1 = A + (bm + r0 + 32) * (size_t)K + bswz;
  const u16* gB0 = B + (bn + r0) * (size_t)K + bswz;
  const u16* gB1 = B + (bn + r0 + 32) * (size_t)K + bswz;
  const u16* gB2 = B + (bn + r0 + 64) * (size_t)K + bswz;
  const u16* gB3 = B + (bn + r0 + 96) * (size_t)K + bswz;

#define FSTAGE(bufi, kk)                                    \
  do {                                                      \
    gload_lds16(gA0 + (kk), &As[bufi][tid * 8]);            \
    gload_lds16(gA1 + (kk), &As[bufi][2048 + tid * 8]);     \
    gload_lds16(gB0 + (kk), &Bs[bufi][tid * 8]);            \
    gload_lds16(gB1 + (kk), &Bs[bufi][2048 + tid * 8]);     \
    gload_lds16(gB2 + (kk), &Bs[bufi][4096 + tid * 8]);     \
    gload_lds16(gB3 + (kk), &Bs[bufi][6144 + tid * 8]);     \
  } while (0)

  FSTAGE(0, 0);
  int buf = 0;
  for (int k0 = 0; k0 < K; k0 += 64) {
    __syncthreads();
    if (k0 + 64 < K) FSTAGE(buf ^ 1, k0 + 64);
    const u16* as = As[buf];
    const u16* bs = Bs[buf];
#pragma unroll
    for (int h = 0; h < 2; ++h) {
      const int cb = quad + 4 * h;
      bf16x8 af[2], bfr[4];
#pragma unroll
      for (int i = 0; i < 2; ++i)
        af[i] = *(const bf16x8*)(&as[(wm + i * 16 + l15) * 64 + ((cb ^ sw) * 8)]);
#pragma unroll
      for (int j = 0; j < 4; ++j)
        bfr[j] = *(const bf16x8*)(&bs[(wn + j * 16 + l15) * 64 + ((cb ^ sw) * 8)]);
#pragma unroll
      for (int i = 0; i < 2; ++i)
#pragma unroll
        for (int j = 0; j < 4; ++j)
          acc[i][j] = __builtin_amdgcn_mfma_f32_16x16x32_bf16(af[i], bfr[j], acc[i][j], 0, 0, 0);
    }
    buf ^= 1;
  }
#undef FSTAGE

  const int rq = quad * 4;
#pragma unroll
  for (int i = 0; i < 2; ++i) {
#pragma unroll
    for (int r = 0; r < 4; ++r) {
      OutT* crow = C + (bm + wm + i * 16 + rq + r) * (size_t)N + bn + wn + l15;
#pragma unroll
      for (int j = 0; j < 4; ++j) {
        if constexpr (sizeof(OutT) == 2)
          crow[j * 16] = f2bf(acc[i][j][r]);
        else
          crow[j * 16] = acc[i][j][r];
      }
    }
  }
}

// ---------------- waveized rmsnorm (blocks 0..1023) + V transpose (1024..1279) ----
__global__ __launch_bounds__(256)
void norm_vtrans_kernel(u16* __restrict__ qkv, const float* __restrict__ qw,
                        const float* __restrict__ kw, u16* __restrict__ vt) {
  const int bid = blockIdx.x;
  const int tid = threadIdx.x;
  if (bid < 1024) {
    const int lane = tid & 63, wv = tid >> 6;
    u16* rp = qkv + (size_t)(bid * 4 + wv) * 1536;
    uint4 qa = *(const uint4*)(rp + lane * 16);
    uint4 qb = *(const uint4*)(rp + lane * 16 + 8);
    uint2 kp = *(const uint2*)(rp + 1024 + lane * 4);
    float qv[16];
    const u32* pa = (const u32*)&qa;
    const u32* pb = (const u32*)&qb;
#pragma unroll
    for (int j = 0; j < 4; ++j) {
      qv[2 * j] = bf2f((u16)pa[j]);
      qv[2 * j + 1] = bf2f((u16)(pa[j] >> 16));
      qv[8 + 2 * j] = bf2f((u16)pb[j]);
      qv[9 + 2 * j] = bf2f((u16)(pb[j] >> 16));
    }
    float k0 = bf2f((u16)kp.x), k1 = bf2f((u16)(kp.x >> 16));
    float k2 = bf2f((u16)kp.y), k3 = bf2f((u16)(kp.y >> 16));
    float ss = 0.f;
#pragma unroll
    for (int j = 0; j < 16; ++j) ss = fmaf(qv[j], qv[j], ss);
    float sk = k0 * k0 + k1 * k1 + k2 * k2 + k3 * k3;
#pragma unroll
    for (int off = 1; off < 64; off <<= 1) {
      ss += __shfl_xor(ss, off);
      sk += __shfl_xor(sk, off);
    }
    const float rn = rsqrtf(ss * (1.0f / 1024.0f) + 1e-6f);
    const float rk = rsqrtf(sk * (1.0f / 256.0f) + 1e-6f);
    float4 w0 = *(const float4*)(qw + lane * 16);
    float4 w1 = *(const float4*)(qw + lane * 16 + 4);
    float4 w2 = *(const float4*)(qw + lane * 16 + 8);
    float4 w3 = *(const float4*)(qw + lane * 16 + 12);
    uint4 o1, o2;
    o1.x = pk2bf(qv[0] * rn * w0.x, qv[1] * rn * w0.y);
    o1.y = pk2bf(qv[2] * rn * w0.z, qv[3] * rn * w0.w);
    o1.z = pk2bf(qv[4] * rn * w1.x, qv[5] * rn * w1.y);
    o1.w = pk2bf(qv[6] * rn * w1.z, qv[7] * rn * w1.w);
    o2.x = pk2bf(qv[8] * rn * w2.x, qv[9] * rn * w2.y);
    o2.y = pk2bf(qv[10] * rn * w2.z, qv[11] * rn * w2.w);
    o2.z = pk2bf(qv[12] * rn * w3.x, qv[13] * rn * w3.y);
    o2.w = pk2bf(qv[14] * rn * w3.z, qv[15] * rn * w3.w);
    *(uint4*)(rp + lane * 16) = o1;
    *(uint4*)(rp + lane * 16 + 8) = o2;
    float4 wk4 = *(const float4*)(kw + lane * 4);
    uint2 ko;
    ko.x = pk2bf(k0 * rk * wk4.x, k1 * rk * wk4.y);
    ko.y = pk2bf(k2 * rk * wk4.z, k3 * rk * wk4.w);
    *(uint2*)(rp + 1024 + lane * 4) = ko;
  } else {
    __shared__ u16 shmem[64 * 72];
    const int e = bid - 1024;
    const int t0 = (e & 31) * 64, kvh = (e >> 5) & 3, b = e >> 7;
    u16(*tile)[72] = (u16(*)[72])shmem;
    const int r = tid >> 2, c16 = (tid & 3) * 16;
    const u16* src = qkv + (size_t)(b * 2048 + t0 + r) * 1536 + 1280 + kvh * 64 + c16;
    *(uint4*)&tile[r][c16] = *(const uint4*)src;
    *(uint4*)&tile[r][c16 + 8] = *(const uint4*)(src + 8);
    __syncthreads();
    const int d = tid >> 2, t16 = (tid & 3) * 16;
    u16 o[16];
#pragma unroll
    for (int j = 0; j < 16; ++j) o[j] = tile[t16 + j][d];
    u16* dst = vt + (size_t)((b * 4 + kvh) * 64 + d) * 2048 + t0 + t16;
    *(uint4*)dst = *(uint4*)&o[0];
    *(uint4*)(dst + 8) = *(uint4*)&o[8];
  }
}

// ---- one head's QK -> softmax(defer-max) -> PV for one 64-key tile ----
// Ps rows are wave-private; head B reuses them after head A with no barrier.
__device__ __forceinline__ void attn_head_tile(
    const u16* __restrict__ Ksb, const u16* __restrict__ Vtsb,
    u16* __restrict__ Ps, const bf16x8 qf0, const bf16x8 qf1,
    const float slope2, f32x4 (&O)[4], float& m_i, float& l_i,
    const int c, const int myq, const int myq_lo, const int myq_hi,
    const int w, const int l15, const int quad, const int swl) {
  const float sc2 = 0.125f * 1.44269504f;
  const float srr1 = slope2, srr2 = slope2 * 2.0f, srr3 = slope2 * 3.0f;
  const float si16 = slope2 * 16.0f;

  f32x4 st[4];
  __builtin_amdgcn_s_setprio(1);
#pragma unroll
  for (int i = 0; i < 4; ++i) {
    const int ro = (i * 16 + l15) * 64;
    bf16x8 a0 = *(const bf16x8*)&Ksb[ro + ((quad ^ swl) * 8)];
    bf16x8 a1 = *(const bf16x8*)&Ksb[ro + (((4 + quad) ^ swl) * 8)];
    f32x4 z = f32x4{0.f, 0.f, 0.f, 0.f};
    z = __builtin_amdgcn_mfma_f32_16x16x32_bf16(a0, qf0, z, 0, 0, 0);
    st[i] = __builtin_amdgcn_mfma_f32_16x16x32_bf16(a1, qf1, z, 0, 0, 0);
  }
  __builtin_amdgcn_s_setprio(0);

  float sv[4][4];
  float rm = -1e30f;
  const bool interior = (c + 63 <= myq_lo) && (c + 512 >= myq_hi);
  if (interior) {
    float bi = slope2 * (float)(c + quad * 4 - myq);
#pragma unroll
    for (int i = 0; i < 4; ++i) {
      float x0 = fmaf(st[i][0], sc2, bi);
      float x1 = fmaf(st[i][1], sc2, bi + srr1);
      float x2 = fmaf(st[i][2], sc2, bi + srr2);
      float x3 = fmaf(st[i][3], sc2, bi + srr3);
      sv[i][0] = x0; sv[i][1] = x1; sv[i][2] = x2; sv[i][3] = x3;
      rm = fmaxf(fmaxf(fmaxf(rm, x0), fmaxf(x1, x2)), x3);
      bi += si16;
    }
  } else {
#pragma unroll
    for (int i = 0; i < 4; ++i)
#pragma unroll
      for (int r = 0; r < 4; ++r) {
        const int key = c + i * 16 + quad * 4 + r;
        const int rel = key - myq;
        float val = (rel > 0 || rel < -512) ? -1e30f
                                            : fmaf(st[i][r], sc2, slope2 * (float)rel);
        sv[i][r] = val;
        rm = fmaxf(rm, val);
      }
  }
  rm = fmaxf(rm, __shfl_xor(rm, 16));
  rm = fmaxf(rm, __shfl_xor(rm, 32));
  // defer-max (T13): skip O-rescale while max growth <= 8 (P bounded by 2^8)
  const bool nskip = !__all(rm <= m_i + 8.0f);
  float mn = m_i;
  if (nskip) mn = fmaxf(m_i, rm);
  float ls = 0.f;
#pragma unroll
  for (int i = 0; i < 4; ++i) {
    float p0 = exp2f(sv[i][0] - mn);
    float p1 = exp2f(sv[i][1] - mn);
    float p2 = exp2f(sv[i][2] - mn);
    float p3 = exp2f(sv[i][3] - mn);
    ls += (p0 + p1) + (p2 + p3);
    uint2 pw;
    pw.x = pk2bf(p0, p1);
    pw.y = pk2bf(p2, p3);
    *(uint2*)&Ps[(w * 16 + l15) * 72 + i * 16 + quad * 4] = pw;
  }
  ls += __shfl_xor(ls, 16);
  ls += __shfl_xor(ls, 32);
  if (nskip) {
    const float alpha = exp2f(m_i - mn);
    l_i *= alpha;
    m_i = mn;
    float ar[4];
#pragma unroll
    for (int r = 0; r < 4; ++r) ar[r] = __shfl(alpha, quad * 4 + r);
#pragma unroll
    for (int jd = 0; jd < 4; ++jd)
#pragma unroll
      for (int r = 0; r < 4; ++r) O[jd][r] *= ar[r];
  }
  l_i += ls;

  bf16x8 pf0 = *(const bf16x8*)&Ps[(w * 16 + l15) * 72 + quad * 8];
  bf16x8 pf1 = *(const bf16x8*)&Ps[(w * 16 + l15) * 72 + 32 + quad * 8];
  __builtin_amdgcn_s_setprio(1);
#pragma unroll
  for (int jd = 0; jd < 4; ++jd) {
    const int ro = (jd * 16 + l15) * 64;
    bf16x8 v0 = *(const bf16x8*)&Vtsb[ro + ((quad ^ swl) * 8)];
    bf16x8 v1 = *(const bf16x8*)&Vtsb[ro + (((4 + quad) ^ swl) * 8)];
    O[jd] = __builtin_amdgcn_mfma_f32_16x16x32_bf16(pf0, v0, O[jd], 0, 0, 0);
    O[jd] = __builtin_amdgcn_mfma_f32_16x16x32_bf16(pf1, v1, O[jd], 0, 0, 0);
  }
  __builtin_amdgcn_s_setprio(0);
}

// ---------------- MFMA flash attention: 128-q blocks, 8 waves, 2 HEADS/block ----
// Heads 2*hp and 2*hp+1 share the same kvh -> identical K/V tiles: staging
// traffic and barrier count per unit of compute halve vs 1 head/block.
__global__ __launch_bounds__(512)
void attn_kernel(const u16* __restrict__ qkvbf, const u16* __restrict__ vt,
                 u16* __restrict__ ybf) {
  __shared__ u16 Ks[2][64 * 64];
  __shared__ u16 Vts[2][64 * 64];
  __shared__ u16 Ps[128 * 72];
  const int qt = blockIdx.x, hp = blockIdx.y, b = blockIdx.z;
  const int h0 = hp * 2, h1 = h0 + 1;
  const int kvh = h0 >> 2, q0 = qt * 128;
  const int tid = threadIdx.x, lane = tid & 63, w = tid >> 6;
  const int l15 = lane & 15, quad = lane >> 4;
  const int swl = l15 & 7;

  const u16* qbase = qkvbf + (size_t)(b * 2048 + q0 + w * 16 + l15) * 1536 + quad * 8;
  const bf16x8 qa0 = *(const bf16x8*)(qbase + h0 * 64);
  const bf16x8 qa1 = *(const bf16x8*)(qbase + h0 * 64 + 32);
  const bf16x8 qb0 = *(const bf16x8*)(qbase + h1 * 64);
  const bf16x8 qb1 = *(const bf16x8*)(qbase + h1 * 64 + 32);

  const int sr = tid >> 3;
  const int bswz = ((tid & 7) ^ (sr & 7)) * 8;
  const u16* kg = qkvbf + (size_t)(b * 2048 + sr) * 1536 + 1024 + kvh * 64 + bswz;
  const u16* vg = vt + (size_t)((b * 4 + kvh) * 64 + sr) * 2048 + bswz;

#define ASTAGE(bufi, cc)                                          \
  do {                                                            \
    gload_lds16(kg + (size_t)(cc) * 1536, &Ks[bufi][tid * 8]);    \
    gload_lds16(vg + (cc), &Vts[bufi][tid * 8]);                  \
  } while (0)

  f32x4 Oa[4], Ob[4];
#pragma unroll
  for (int jd = 0; jd < 4; ++jd) {
    Oa[jd] = f32x4{0.f, 0.f, 0.f, 0.f};
    Ob[jd] = f32x4{0.f, 0.f, 0.f, 0.f};
  }
  float ma = -1e30f, la = 0.f, mb = -1e30f, lb = 0.f;
  const float LOG2E = 1.44269504f;
  const float slope_a = exp2f(-0.5f * (float)(h0 + 1)) * LOG2E;
  const float slope_b = exp2f(-0.5f * (float)(h1 + 1)) * LOG2E;
  const int c_lo = (q0 >= 512) ? (q0 - 512) : 0;
  const int c_hi = q0 + 64;
  const int myq_lo = q0 + w * 16;
  const int myq_hi = myq_lo + 15;
  const int myq = myq_lo + l15;

  ASTAGE(0, c_lo);
  int buf = 0;

  for (int c = c_lo; c <= c_hi; c += 64) {
    __syncthreads();  // publishes buf (drains vmcnt), prev compute done
    if (c + 64 <= c_hi) ASTAGE(buf ^ 1, c + 64);

    if (!(c > myq_hi || c + 63 < myq_lo - 512)) {
      attn_head_tile(Ks[buf], Vts[buf], Ps, qa0, qa1, slope_a, Oa, ma, la,
                     c, myq, myq_lo, myq_hi, w, l15, quad, swl);
      attn_head_tile(Ks[buf], Vts[buf], Ps, qb0, qb1, slope_b, Ob, mb, lb,
                     c, myq, myq_lo, myq_hi, w, l15, quad, swl);
    }
    buf ^= 1;
  }
#undef ASTAGE

  float lra[4], lrb[4];
#pragma unroll
  for (int r = 0; r < 4; ++r) {
    lra[r] = __shfl(la, quad * 4 + r);
    lrb[r] = __shfl(lb, quad * 4 + r);
  }
#pragma unroll
  for (int r = 0; r < 4; ++r) {
    const float inva = 1.0f / lra[r];
    const float invb = 1.0f / lrb[r];
    u16* orow = ybf + (size_t)(b * 2048 + q0 + w * 16 + quad * 4 + r) * 1024 + l15;
#pragma unroll
    for (int jd = 0; jd < 4; ++jd) {
      orow[h0 * 64 + jd * 16] = f2bf(Oa[jd][r] * inva);
      orow[h1 * 64 + jd * 16] = f2bf(Ob[jd][r] * invb);
    }
  }
}

// ---------------- launch ----------------
extern "C" void kernel_launch(void* const* d_in, const int* in_sizes, int n_in,
                              void* d_out, int out_size, void* d_ws, size_t ws_size,
                              hipStream_t stream) {
  const float* x = (const float*)d_in[0];
  const float* wq = (const float*)d_in[1];
  const float* wk = (const float*)d_in[2];
  const float* wv = (const float*)d_in[3];
  const float* wo = (const float*)d_in[4];
  const float* qnw = (const float*)d_in[5];
  const float* knw = (const float*)d_in[6];
  float* out = (float*)d_out;
  char* ws = (char*)d_ws;

  u16* x_bf = (u16*)(ws);                     // 4096x1024
  u16* wcat_bf = (u16*)(ws + 8388608);        // 1536x1024
  u16* wo_bf = (u16*)(ws + 11534336);         // 1024x1024
  u16* qkv_bf = (u16*)(ws + 13631488);        // 4096x1536
  u16* vt_bf = (u16*)(ws + 26214400);         // 2x4x64x2048
  u16* y_bf = (u16*)(ws + 28311552);          // 4096x1024

  cvt_all_kernel<<<6656, 256, 0, stream>>>(x, wq, wk, wv, wo, x_bf, wcat_bf, wo_bf);

  gemm_bt_kernel<u16><<<dim3(12, 64), 256, 0, stream>>>(x_bf, wcat_bf, qkv_bf, 4096, 1536, 1024);
  norm_vtrans_kernel<<<1280, 256, 0, stream>>>(qkv_bf, qnw, knw, vt_bf);
  attn_kernel<<<dim3(16, 8, 2), 512, 0, stream>>>(qkv_bf, vt_bf, y_bf);
  gemm_bt_kernel<float><<<dim3(8, 64), 256, 0, stream>>>(y_bf, wo_bf, out, 4096, 1024, 1024);
}

// Round 8
// 153.611 us; speedup vs baseline: 1.0342x; 1.0342x over previous
//
#include <hip/hip_runtime.h>

typedef unsigned short u16;
typedef unsigned int u32;

typedef __bf16 bf16x8 __attribute__((ext_vector_type(8)));
typedef float f32x4 __attribute__((ext_vector_type(4)));

__device__ __forceinline__ u16 f2bf(float f) {
  __bf16 h = (__bf16)f;
  return __builtin_bit_cast(u16, h);
}
__device__ __forceinline__ u32 pk2bf(float a, float b) {
  __bf16 lo = (__bf16)a, hi = (__bf16)b;
  return (u32)__builtin_bit_cast(u16, lo) | ((u32)__builtin_bit_cast(u16, hi) << 16);
}
__device__ __forceinline__ float bf2f(u16 v) {
  u32 u = (u32)v << 16;
  return __builtin_bit_cast(float, u);
}

typedef const __attribute__((address_space(1))) u32 gbl_u32;
typedef __attribute__((address_space(3))) u32 lds_u32;
__device__ __forceinline__ void gload_lds16(const u16* g, u16* l) {
  __builtin_amdgcn_global_load_lds((gbl_u32*)g, (lds_u32*)l, 16, 0, 0);
}

// ---------------- fused f32 -> bf16 convert for all 5 tensors ----------------
__global__ __launch_bounds__(256)
void cvt_all_kernel(const float* __restrict__ x, const float* __restrict__ wq,
                    const float* __restrict__ wk, const float* __restrict__ wv,
                    const float* __restrict__ wo, u16* __restrict__ x_bf,
                    u16* __restrict__ wcat_bf, u16* __restrict__ wo_bf) {
  int t = blockIdx.x * 256 + threadIdx.x;
  const float* src;
  u16* dst;
  if (t < 1048576) {
    src = x; dst = x_bf;
  } else if (t < 1310720) {
    src = wq; dst = wcat_bf; t -= 1048576;
  } else if (t < 1376256) {
    src = wk; dst = wcat_bf + 1048576; t -= 1310720;
  } else if (t < 1441792) {
    src = wv; dst = wcat_bf + 1310720; t -= 1376256;
  } else {
    src = wo; dst = wo_bf; t -= 1441792;
  }
  const int i = t * 4;
  float4 v = *(const float4*)(src + i);
  uint2 p;
  p.x = pk2bf(v.x, v.y);
  p.y = pk2bf(v.z, v.w);
  *(uint2*)(dst + i) = p;
}

// ---------------- bf16 MFMA GEMM: C[M][N] = A[M][K] * B[N][K]^T ----------------
// 64x128 tile, BK=64, 4 waves 2x2 (wave tile 32x64). Double-buffered
// global_load_lds width=16, ONE barrier per K-step. XOR swizzle (blk ^= row&7)
// on the global source address (LDS dest linear); fragment reads same XOR.
// Verified. QKV grid 768 = 3 blocks/CU; out-proj 512 = 2/CU. Established
// constraint (R5/R7): never drop below 2 blocks/CU in this pipeline.
template <typename OutT>
__global__ __launch_bounds__(256)
void gemm_bt_kernel(const u16* __restrict__ A, const u16* __restrict__ B,
                    OutT* __restrict__ C, int M, int N, int K) {
  __shared__ u16 As[2][64 * 64];
  __shared__ u16 Bs[2][128 * 64];
  const int tid = threadIdx.x;
  const int lane = tid & 63;
  const int wave = tid >> 6;
  const int wm = (wave >> 1) * 32;
  const int wn = (wave & 1) * 64;
  const int l15 = lane & 15;
  const int quad = lane >> 4;
  const int sw = l15 & 7;
  const size_t bm = (size_t)blockIdx.y * 64;
  const size_t bn = (size_t)blockIdx.x * 128;

  f32x4 acc[2][4];
#pragma unroll
  for (int i = 0; i < 2; ++i)
#pragma unroll
    for (int j = 0; j < 4; ++j) acc[i][j] = f32x4{0.f, 0.f, 0.f, 0.f};

  const int r0 = tid >> 3;
  const int bswz = ((tid & 7) ^ (r0 & 7)) * 8;
  const u16* gA0 = A + (bm + r0) * (size_t)K + bswz;
  const u16* gA1 = A + (bm + r0 + 32) * (size_t)K + bswz;
  const u16* gB0 = B + (bn + r0) * (size_t)K + bswz;
  const u16* gB1 = B + (bn + r0 + 32) * (size_t)K + bswz;
  const u16* gB2 = B + (bn + r0 + 64) * (size_t)K + bswz;
  const u16* gB3 = B + (bn + r0 + 96) * (size_t)K + bswz;

#define FSTAGE(bufi, kk)                                    \
  do {                                                      \
    gload_lds16(gA0 + (kk), &As[bufi][tid * 8]);            \
    gload_lds16(gA1 + (kk), &As[bufi][2048 + tid * 8]);     \
    gload_lds16(gB0 + (kk), &Bs[bufi][tid * 8]);            \
    gload_lds16(gB1 + (kk), &Bs[bufi][2048 + tid * 8]);     \
    gload_lds16(gB2 + (kk), &Bs[bufi][4096 + tid * 8]);     \
    gload_lds16(gB3 + (kk), &Bs[bufi][6144 + tid * 8]);     \
  } while (0)

  FSTAGE(0, 0);
  int buf = 0;
  for (int k0 = 0; k0 < K; k0 += 64) {
    __syncthreads();
    if (k0 + 64 < K) FSTAGE(buf ^ 1, k0 + 64);
    const u16* as = As[buf];
    const u16* bs = Bs[buf];
#pragma unroll
    for (int h = 0; h < 2; ++h) {
      const int cb = quad + 4 * h;
      bf16x8 af[2], bfr[4];
#pragma unroll
      for (int i = 0; i < 2; ++i)
        af[i] = *(const bf16x8*)(&as[(wm + i * 16 + l15) * 64 + ((cb ^ sw) * 8)]);
#pragma unroll
      for (int j = 0; j < 4; ++j)
        bfr[j] = *(const bf16x8*)(&bs[(wn + j * 16 + l15) * 64 + ((cb ^ sw) * 8)]);
#pragma unroll
      for (int i = 0; i < 2; ++i)
#pragma unroll
        for (int j = 0; j < 4; ++j)
          acc[i][j] = __builtin_amdgcn_mfma_f32_16x16x32_bf16(af[i], bfr[j], acc[i][j], 0, 0, 0);
    }
    buf ^= 1;
  }
#undef FSTAGE

  const int rq = quad * 4;
#pragma unroll
  for (int i = 0; i < 2; ++i) {
#pragma unroll
    for (int r = 0; r < 4; ++r) {
      OutT* crow = C + (bm + wm + i * 16 + rq + r) * (size_t)N + bn + wn + l15;
#pragma unroll
      for (int j = 0; j < 4; ++j) {
        if constexpr (sizeof(OutT) == 2)
          crow[j * 16] = f2bf(acc[i][j][r]);
        else
          crow[j * 16] = acc[i][j][r];
      }
    }
  }
}

// ---------------- waveized rmsnorm (blocks 0..1023) + V transpose (1024..1279) ----
// One wave per row: 16 Q elems + 4 K elems per lane, pure shfl_xor reduce,
// no LDS, no barrier. 4 rows per 256-thread block.
__global__ __launch_bounds__(256)
void norm_vtrans_kernel(u16* __restrict__ qkv, const float* __restrict__ qw,
                        const float* __restrict__ kw, u16* __restrict__ vt) {
  const int bid = blockIdx.x;
  const int tid = threadIdx.x;
  if (bid < 1024) {
    const int lane = tid & 63, wv = tid >> 6;
    u16* rp = qkv + (size_t)(bid * 4 + wv) * 1536;
    uint4 qa = *(const uint4*)(rp + lane * 16);
    uint4 qb = *(const uint4*)(rp + lane * 16 + 8);
    uint2 kp = *(const uint2*)(rp + 1024 + lane * 4);
    float qv[16];
    const u32* pa = (const u32*)&qa;
    const u32* pb = (const u32*)&qb;
#pragma unroll
    for (int j = 0; j < 4; ++j) {
      qv[2 * j] = bf2f((u16)pa[j]);
      qv[2 * j + 1] = bf2f((u16)(pa[j] >> 16));
      qv[8 + 2 * j] = bf2f((u16)pb[j]);
      qv[9 + 2 * j] = bf2f((u16)(pb[j] >> 16));
    }
    float k0 = bf2f((u16)kp.x), k1 = bf2f((u16)(kp.x >> 16));
    float k2 = bf2f((u16)kp.y), k3 = bf2f((u16)(kp.y >> 16));
    float ss = 0.f;
#pragma unroll
    for (int j = 0; j < 16; ++j) ss = fmaf(qv[j], qv[j], ss);
    float sk = k0 * k0 + k1 * k1 + k2 * k2 + k3 * k3;
#pragma unroll
    for (int off = 1; off < 64; off <<= 1) {
      ss += __shfl_xor(ss, off);
      sk += __shfl_xor(sk, off);
    }
    const float rn = rsqrtf(ss * (1.0f / 1024.0f) + 1e-6f);
    const float rk = rsqrtf(sk * (1.0f / 256.0f) + 1e-6f);
    float4 w0 = *(const float4*)(qw + lane * 16);
    float4 w1 = *(const float4*)(qw + lane * 16 + 4);
    float4 w2 = *(const float4*)(qw + lane * 16 + 8);
    float4 w3 = *(const float4*)(qw + lane * 16 + 12);
    uint4 o1, o2;
    o1.x = pk2bf(qv[0] * rn * w0.x, qv[1] * rn * w0.y);
    o1.y = pk2bf(qv[2] * rn * w0.z, qv[3] * rn * w0.w);
    o1.z = pk2bf(qv[4] * rn * w1.x, qv[5] * rn * w1.y);
    o1.w = pk2bf(qv[6] * rn * w1.z, qv[7] * rn * w1.w);
    o2.x = pk2bf(qv[8] * rn * w2.x, qv[9] * rn * w2.y);
    o2.y = pk2bf(qv[10] * rn * w2.z, qv[11] * rn * w2.w);
    o2.z = pk2bf(qv[12] * rn * w3.x, qv[13] * rn * w3.y);
    o2.w = pk2bf(qv[14] * rn * w3.z, qv[15] * rn * w3.w);
    *(uint4*)(rp + lane * 16) = o1;
    *(uint4*)(rp + lane * 16 + 8) = o2;
    float4 wk4 = *(const float4*)(kw + lane * 4);
    uint2 ko;
    ko.x = pk2bf(k0 * rk * wk4.x, k1 * rk * wk4.y);
    ko.y = pk2bf(k2 * rk * wk4.z, k3 * rk * wk4.w);
    *(uint2*)(rp + 1024 + lane * 4) = ko;
  } else {
    __shared__ u16 shmem[64 * 72];
    const int e = bid - 1024;
    const int t0 = (e & 31) * 64, kvh = (e >> 5) & 3, b = e >> 7;
    u16(*tile)[72] = (u16(*)[72])shmem;
    const int r = tid >> 2, c16 = (tid & 3) * 16;
    const u16* src = qkv + (size_t)(b * 2048 + t0 + r) * 1536 + 1280 + kvh * 64 + c16;
    *(uint4*)&tile[r][c16] = *(const uint4*)src;
    *(uint4*)&tile[r][c16 + 8] = *(const uint4*)(src + 8);
    __syncthreads();
    const int d = tid >> 2, t16 = (tid & 3) * 16;
    u16 o[16];
#pragma unroll
    for (int j = 0; j < 16; ++j) o[j] = tile[t16 + j][d];
    u16* dst = vt + (size_t)((b * 4 + kvh) * 64 + d) * 2048 + t0 + t16;
    *(uint4*)dst = *(uint4*)&o[0];
    *(uint4*)(dst + 8) = *(uint4*)&o[8];
  }
}

// ---------------- MFMA flash attention: 128-q blocks, 8 waves (R6-verified) ----
// 1 head/block, grid 512 = 2 blocks/CU (2-heads/block at 1/CU regressed
// +4.6us in R7 -- keep this shape). Double-buffered global_load_lds K/V,
// ONE barrier per kv-tile, defer-max (T13), setprio around MFMA clusters.
__global__ __launch_bounds__(512)
void attn_kernel(const u16* __restrict__ qkvbf, const u16* __restrict__ vt,
                 u16* __restrict__ ybf) {
  __shared__ u16 Ks[2][64 * 64];
  __shared__ u16 Vts[2][64 * 64];
  __shared__ u16 Ps[128 * 72];
  const int qt = blockIdx.x, h = blockIdx.y, b = blockIdx.z;
  const int kvh = h >> 2, q0 = qt * 128;
  const int tid = threadIdx.x, lane = tid & 63, w = tid >> 6;
  const int l15 = lane & 15, quad = lane >> 4;
  const int swl = l15 & 7;

  const u16* qrow = qkvbf + (size_t)(b * 2048 + q0 + w * 16 + l15) * 1536 + h * 64 + quad * 8;
  const bf16x8 qf0 = *(const bf16x8*)qrow;
  const bf16x8 qf1 = *(const bf16x8*)(qrow + 32);

  const int sr = tid >> 3;
  const int bswz = ((tid & 7) ^ (sr & 7)) * 8;
  const u16* kg = qkvbf + (size_t)(b * 2048 + sr) * 1536 + 1024 + kvh * 64 + bswz;
  const u16* vg = vt + (size_t)((b * 4 + kvh) * 64 + sr) * 2048 + bswz;

#define ASTAGE(bufi, cc)                                          \
  do {                                                            \
    gload_lds16(kg + (size_t)(cc) * 1536, &Ks[bufi][tid * 8]);    \
    gload_lds16(vg + (cc), &Vts[bufi][tid * 8]);                  \
  } while (0)

  f32x4 O[4];
#pragma unroll
  for (int jd = 0; jd < 4; ++jd) O[jd] = f32x4{0.f, 0.f, 0.f, 0.f};
  float m_i = -1e30f, l_i = 0.f;
  const float LOG2E = 1.44269504f;
  const float sc2 = 0.125f * LOG2E;
  const float slope2 = exp2f(-0.5f * (float)(h + 1)) * LOG2E;
  const int c_lo = (q0 >= 512) ? (q0 - 512) : 0;
  const int c_hi = q0 + 64;
  const int myq_lo = q0 + w * 16;
  const int myq_hi = myq_lo + 15;
  const int myq = myq_lo + l15;
  const float srr1 = slope2, srr2 = slope2 * 2.0f, srr3 = slope2 * 3.0f;
  const float si16 = slope2 * 16.0f;

  ASTAGE(0, c_lo);
  int buf = 0;

  for (int c = c_lo; c <= c_hi; c += 64) {
    __syncthreads();
    if (c + 64 <= c_hi) ASTAGE(buf ^ 1, c + 64);

    if (!(c > myq_hi || c + 63 < myq_lo - 512)) {
      f32x4 st[4];
      __builtin_amdgcn_s_setprio(1);
#pragma unroll
      for (int i = 0; i < 4; ++i) {
        const int ro = (i * 16 + l15) * 64;
        bf16x8 a0 = *(const bf16x8*)&Ks[buf][ro + ((quad ^ swl) * 8)];
        bf16x8 a1 = *(const bf16x8*)&Ks[buf][ro + (((4 + quad) ^ swl) * 8)];
        f32x4 z = f32x4{0.f, 0.f, 0.f, 0.f};
        z = __builtin_amdgcn_mfma_f32_16x16x32_bf16(a0, qf0, z, 0, 0, 0);
        st[i] = __builtin_amdgcn_mfma_f32_16x16x32_bf16(a1, qf1, z, 0, 0, 0);
      }
      __builtin_amdgcn_s_setprio(0);

      float sv[4][4];
      float rm = -1e30f;
      const bool interior = (c + 63 <= myq_lo) && (c + 512 >= myq_hi);
      if (interior) {
        float bi = slope2 * (float)(c + quad * 4 - myq);
#pragma unroll
        for (int i = 0; i < 4; ++i) {
          float x0 = fmaf(st[i][0], sc2, bi);
          float x1 = fmaf(st[i][1], sc2, bi + srr1);
          float x2 = fmaf(st[i][2], sc2, bi + srr2);
          float x3 = fmaf(st[i][3], sc2, bi + srr3);
          sv[i][0] = x0; sv[i][1] = x1; sv[i][2] = x2; sv[i][3] = x3;
          rm = fmaxf(fmaxf(fmaxf(rm, x0), fmaxf(x1, x2)), x3);
          bi += si16;
        }
      } else {
#pragma unroll
        for (int i = 0; i < 4; ++i)
#pragma unroll
          for (int r = 0; r < 4; ++r) {
            const int key = c + i * 16 + quad * 4 + r;
            const int rel = key - myq;
            float val = (rel > 0 || rel < -512) ? -1e30f
                                                : fmaf(st[i][r], sc2, slope2 * (float)rel);
            sv[i][r] = val;
            rm = fmaxf(rm, val);
          }
      }
      rm = fmaxf(rm, __shfl_xor(rm, 16));
      rm = fmaxf(rm, __shfl_xor(rm, 32));
      // defer-max (T13): wave-uniform skip of the rescale when max growth <= 8
      const bool nskip = !__all(rm <= m_i + 8.0f);
      float mn = m_i;
      if (nskip) mn = fmaxf(m_i, rm);
      float ls = 0.f;
#pragma unroll
      for (int i = 0; i < 4; ++i) {
        float p0 = exp2f(sv[i][0] - mn);
        float p1 = exp2f(sv[i][1] - mn);
        float p2 = exp2f(sv[i][2] - mn);
        float p3 = exp2f(sv[i][3] - mn);
        ls += (p0 + p1) + (p2 + p3);
        uint2 pw;
        pw.x = pk2bf(p0, p1);
        pw.y = pk2bf(p2, p3);
        *(uint2*)&Ps[(w * 16 + l15) * 72 + i * 16 + quad * 4] = pw;
      }
      ls += __shfl_xor(ls, 16);
      ls += __shfl_xor(ls, 32);
      if (nskip) {
        const float alpha = exp2f(m_i - mn);
        l_i *= alpha;
        m_i = mn;
        float ar[4];
#pragma unroll
        for (int r = 0; r < 4; ++r) ar[r] = __shfl(alpha, quad * 4 + r);
#pragma unroll
        for (int jd = 0; jd < 4; ++jd)
#pragma unroll
          for (int r = 0; r < 4; ++r) O[jd][r] *= ar[r];
      }
      l_i += ls;

      bf16x8 pf0 = *(const bf16x8*)&Ps[(w * 16 + l15) * 72 + quad * 8];
      bf16x8 pf1 = *(const bf16x8*)&Ps[(w * 16 + l15) * 72 + 32 + quad * 8];
      __builtin_amdgcn_s_setprio(1);
#pragma unroll
      for (int jd = 0; jd < 4; ++jd) {
        const int ro = (jd * 16 + l15) * 64;
        bf16x8 v0 = *(const bf16x8*)&Vts[buf][ro + ((quad ^ swl) * 8)];
        bf16x8 v1 = *(const bf16x8*)&Vts[buf][ro + (((4 + quad) ^ swl) * 8)];
        O[jd] = __builtin_amdgcn_mfma_f32_16x16x32_bf16(pf0, v0, O[jd], 0, 0, 0);
        O[jd] = __builtin_amdgcn_mfma_f32_16x16x32_bf16(pf1, v1, O[jd], 0, 0, 0);
      }
      __builtin_amdgcn_s_setprio(0);
    }
    buf ^= 1;
  }
#undef ASTAGE

  float lr[4];
#pragma unroll
  for (int r = 0; r < 4; ++r) lr[r] = __shfl(l_i, quad * 4 + r);
#pragma unroll
  for (int r = 0; r < 4; ++r) {
    const float inv = 1.0f / lr[r];
    u16* orow = ybf + (size_t)(b * 2048 + q0 + w * 16 + quad * 4 + r) * 1024 + h * 64 + l15;
#pragma unroll
    for (int jd = 0; jd < 4; ++jd) orow[jd * 16] = f2bf(O[jd][r] * inv);
  }
}

// ---------------- launch ----------------
extern "C" void kernel_launch(void* const* d_in, const int* in_sizes, int n_in,
                              void* d_out, int out_size, void* d_ws, size_t ws_size,
                              hipStream_t stream) {
  const float* x = (const float*)d_in[0];
  const float* wq = (const float*)d_in[1];
  const float* wk = (const float*)d_in[2];
  const float* wv = (const float*)d_in[3];
  const float* wo = (const float*)d_in[4];
  const float* qnw = (const float*)d_in[5];
  const float* knw = (const float*)d_in[6];
  float* out = (float*)d_out;
  char* ws = (char*)d_ws;

  u16* x_bf = (u16*)(ws);                     // 4096x1024
  u16* wcat_bf = (u16*)(ws + 8388608);        // 1536x1024
  u16* wo_bf = (u16*)(ws + 11534336);         // 1024x1024
  u16* qkv_bf = (u16*)(ws + 13631488);        // 4096x1536
  u16* vt_bf = (u16*)(ws + 26214400);         // 2x4x64x2048
  u16* y_bf = (u16*)(ws + 28311552);          // 4096x1024

  cvt_all_kernel<<<6656, 256, 0, stream>>>(x, wq, wk, wv, wo, x_bf, wcat_bf, wo_bf);

  gemm_bt_kernel<u16><<<dim3(12, 64), 256, 0, stream>>>(x_bf, wcat_bf, qkv_bf, 4096, 1536, 1024);
  norm_vtrans_kernel<<<1280, 256, 0, stream>>>(qkv_bf, qnw, knw, vt_bf);
  attn_kernel<<<dim3(16, 16, 2), 512, 0, stream>>>(qkv_bf, vt_bf, y_bf);
  gemm_bt_kernel<float><<<dim3(8, 64), 256, 0, stream>>>(y_bf, wo_bf, out, 4096, 1024, 1024);
}